// Round 21
// baseline (77.370 us; speedup 1.0000x reference)
//
#include <hip/hip_runtime.h>
#include <hip/hip_bf16.h>
#include <stdint.h>

#define N_ROWS 8192
#define DIM    1024
#define INV_T  14.2857142857142857f   // 1/0.07
#define SCL    (INV_T / 1024.0f)      // acc holds 1024*sim (values packed as 32*x)
#define C1     (SCL * 1.44269504088896f)  // SCL * log2(e): e = exp2(acc*C1)
#define NCLS   1000

#define BM   128
#define RPB  512                 // row pitch bytes (fp4: DIM/2)
#define TKB  64                  // K-tile bytes per row (128 k-elems * 0.5B)
#define NTILE  (N_ROWS / BM)     // 64
#define NSLICE (2 * NTILE)       // 128 col-slices of 64
#define NKT    8                 // 1024 / 128
#define NPAIR  2080              // 64 diag + 64*63/2 off-diag
#define PER_XCD (NPAIR / 8)      // 260

typedef int   i32x4 __attribute__((ext_vector_type(4)));
typedef int   i32x8 __attribute__((ext_vector_type(8)));
typedef float f32x4 __attribute__((ext_vector_type(4)));

// e2m1 encode of y (round-to-nearest): values 0,.5,1,1.5,2,3,4,6 + sign bit
__device__ __forceinline__ unsigned e2m1(float y) {
    const float a = fabsf(y);
    unsigned c = a < 0.25f ? 0u : a < 0.75f ? 1u : a < 1.25f ? 2u :
                 a < 1.75f ? 3u : a < 2.5f  ? 4u : a < 3.5f  ? 5u :
                 a < 5.0f  ? 6u : 7u;
    return c | (y < 0.f ? 8u : 0u);
}

// ---------------- kernel 1: row-normalize f32 -> fp4 e2m1 (x32 prescale) ----
// One WAVE per row. Block 0 / thread 0 also zeroes out[0].
__global__ __launch_bounds__(256) void norm_kernel(
    const float* __restrict__ V, unsigned char* __restrict__ A4,
    float* __restrict__ out)
{
    if (blockIdx.x == 0 && threadIdx.x == 0) out[0] = 0.f;

    const int wid  = threadIdx.x >> 6;
    const int lane = threadIdx.x & 63;
    const int row  = blockIdx.x * 4 + wid;

    const float4* vp = (const float4*)(V + (size_t)row * DIM);
    float4 v[4];
    float ss = 0.f;
    #pragma unroll
    for (int i = 0; i < 4; ++i) {
        v[i] = vp[lane + i * 64];
        ss += v[i].x*v[i].x + v[i].y*v[i].y + v[i].z*v[i].z + v[i].w*v[i].w;
    }
    #pragma unroll
    for (int off = 1; off < 64; off <<= 1) ss += __shfl_xor(ss, off, 64);
    const float inv = 32.0f / sqrtf(ss);

    unsigned short op[4];
    #pragma unroll
    for (int i = 0; i < 4; ++i) {
        const unsigned e0 = e2m1(v[i].x * inv), e1 = e2m1(v[i].y * inv);
        const unsigned e2 = e2m1(v[i].z * inv), e3 = e2m1(v[i].w * inv);
        op[i] = (unsigned short)(e0 | (e1 << 4) | (e2 << 8) | (e3 << 12));
    }
    unsigned char* dst = A4 + (size_t)row * RPB;
    #pragma unroll
    for (int i = 0; i < 4; ++i)
        ((unsigned short*)dst)[lane + i * 64] = op[i];
}

// ---------------- kernel 2: fused symmetric sim GEMM (MX-fp4) + epilogue ----------------
// R20 shell. R21 delta: __launch_bounds__(256) with NO min-blocks arg.
// Session law: the 2nd arg sets a hard VGPR band on this toolchain
// ((256,4) -> 64-cap spill disaster; (256,3) -> we use 84 of ~170).
// HW occupancy is set by ACTUAL use: VGPR 84 allows 6 waves/SIMD and
// LDS 32768B allows exactly 5 blocks/CU (160 KiB) -> dropping the arg
// should lift residency 3 -> 5 blocks/CU with unchanged codegen.
__global__ __launch_bounds__(256) void sim_kernel(
    const unsigned char* __restrict__ A4, const int* __restrict__ labels,
    float2* __restrict__ pp)
{
    __shared__ __align__(16) unsigned char As[2][BM * TKB];   // 2 x 8 KB
    __shared__ __align__(16) unsigned char Bs[2][BM * TKB];   // 2 x 8 KB

    // ---- supertile pair decode (uniform per block, scalar) ----
    const int b = blockIdx.x;                    // 0..2079
    const int v = (b & 7) * PER_XCD + (b >> 3);  // XCD-contiguous virtual index
    int rem = v, RT = 0, rowsz = 36 + 7 * 64;    // ST-row RT size
    while (rem >= rowsz) { rem -= rowsz; ++RT; rowsz -= 64; }
    int rt, ct;
    if (rem < 36) {                              // diagonal supertile
        int i = 0, left = 8;
        while (rem >= left) { rem -= left; ++i; --left; }
        rt = RT * 8 + i;  ct = RT * 8 + i + rem;
    } else {                                     // off-diagonal supertile
        const int o  = rem - 36;
        const int CT = RT + 1 + (o >> 6);
        const int w  = o & 63;
        rt = RT * 8 + (w >> 3);
        ct = CT * 8 + (w & 7);
    }
    const bool isDiag = (rt == ct);

    const int tid  = threadIdx.x;
    const int lane = tid & 63;
    const int wid  = tid >> 6;
    const int wr   = wid >> 1;      // wave row 0..1
    const int wc   = wid & 1;       // wave col 0..1

    const int rbase = rt * BM;
    const int cbase = ct * BM;

    const int t = lane >> 4;        // K-group 0..3 / row sub-block
    const int j = lane & 15;

    const int rowq = rbase + wr * 64 + (t << 2);
    const int col0 = cbase + wc * 64 + j;

    int labr[16];
    #pragma unroll
    for (int m = 0; m < 4; ++m)
        #pragma unroll
        for (int r = 0; r < 4; ++r)
            labr[m * 4 + r] = labels[rowq + m * 16 + r];
    int labc[4];
    #pragma unroll
    for (int n = 0; n < 4; ++n) labc[n] = labels[col0 + n * 16];

    f32x4 acc[4][4];
    #pragma unroll
    for (int m = 0; m < 4; ++m)
        #pragma unroll
        for (int n = 0; n < 4; ++n)
            acc[m][n] = (f32x4){0.f, 0.f, 0.f, 0.f};

    // staging: linear LDS dest; source 16B-chunk XOR-swizzled with
    // f(row) = (row&3)^((row>>2)&3); read applies the same XOR.
    const unsigned char* sgA[2];
    const unsigned char* sgB[2];
    #pragma unroll
    for (int i = 0; i < 2; ++i) {
        const int c    = i * 256 + tid;
        const int rowc = c >> 2;
        const int kcs  = (c & 3) ^ (rowc & 3) ^ ((rowc >> 2) & 3);
        sgA[i] = A4 + (size_t)(rbase + rowc) * RPB + kcs * 16;
        sgB[i] = A4 + (size_t)(cbase + rowc) * RPB + kcs * 16;
    }
    #define STAGE(buf, kOff)                                                       \
    {                                                                              \
        _Pragma("unroll")                                                          \
        for (int i = 0; i < 2; ++i) {                                              \
            const int ldsOff = i * 4096 + wid * 1024;   /* +lane*16 by HW */       \
            __builtin_amdgcn_global_load_lds(                                      \
                (const __attribute__((address_space(1))) void*)(sgA[i] + (kOff)),  \
                (__attribute__((address_space(3))) void*)(As[buf] + ldsOff),       \
                16, 0, 0);                                                         \
            __builtin_amdgcn_global_load_lds(                                      \
                (const __attribute__((address_space(1))) void*)(sgB[i] + (kOff)),  \
                (__attribute__((address_space(3))) void*)(Bs[buf] + ldsOff),       \
                16, 0, 0);                                                         \
        }                                                                          \
    }

    // read-side chunk offset: f(row) = (j&3)^((j>>2)&3), indep. of m/n.
    const int ph = ((t ^ (j & 3) ^ ((j >> 2) & 3)) << 4);

    const i32x4 Z4 = (i32x4){0, 0, 0, 0};

    STAGE(0, 0);
    __syncthreads();                // tile 0 resident

    int cur = 0;
    for (int kt = 0; kt < NKT; ++kt) {
        // ---- pull all fragments of tile kt from buf[cur]
        i32x8 a8[4], b8[4];
        #pragma unroll
        for (int m = 0; m < 4; ++m) {
            const int rowa = wr * 64 + m * 16 + j;
            i32x4 q = *(const i32x4*)(As[cur] + rowa * TKB + ph);
            a8[m] = __builtin_shufflevector(q, Z4, 0, 1, 2, 3, 4, 5, 6, 7);
        }
        #pragma unroll
        for (int n = 0; n < 4; ++n) {
            const int rowb = wc * 64 + n * 16 + j;
            i32x4 q = *(const i32x4*)(Bs[cur] + rowb * TKB + ph);
            b8[n] = __builtin_shufflevector(q, Z4, 0, 1, 2, 3, 4, 5, 6, 7);
        }

        // ---- prefetch next tile into the other buffer (no hazard with reads)
        if (kt + 1 < NKT) STAGE(cur ^ 1, (kt + 1) * TKB);

        __builtin_amdgcn_s_setprio(1);
        #pragma unroll
        for (int m = 0; m < 4; ++m)
            #pragma unroll
            for (int n = 0; n < 4; ++n)
                acc[m][n] = __builtin_amdgcn_mfma_scale_f32_16x16x128_f8f6f4(
                    a8[m], b8[n], acc[m][n],
                    4 /*A fmt fp4*/, 4 /*B fmt fp4*/,
                    0, 0x7F /*scaleA = 2^0*/, 0, 0x7F /*scaleB = 2^0*/);
        __builtin_amdgcn_s_setprio(0);

        // single barrier per K-tile: drains lgkm (reads of cur done block-wide)
        // and vmcnt (prefetch into cur^1 landed block-wide).
        __syncthreads();
        cur ^= 1;
    }

    // ---------------- epilogue (sum of exp + raw-acc positive sum) ----------
    float sum_p[16], pos_p[16];
    #pragma unroll
    for (int i = 0; i < 16; ++i) { sum_p[i] = 0.f; pos_p[i] = 0.f; }
    float csum[4], cpos[4];
    #pragma unroll
    for (int n = 0; n < 4; ++n) { csum[n] = 0.f; cpos[n] = 0.f; }

    if (isDiag) {
        #pragma unroll
        for (int m = 0; m < 4; ++m)
            #pragma unroll
            for (int n = 0; n < 4; ++n) {
                const int gcol = col0 + n * 16;
                #pragma unroll
                for (int r = 0; r < 4; ++r) {
                    const float a    = acc[m][n][r];
                    const int   i16  = m * 4 + r;
                    const int   grow = rowq + m * 16 + r;
                    const bool  diag = (grow == gcol);
                    const float e    = diag ? 0.f : __builtin_amdgcn_exp2f(a * C1);
                    sum_p[i16] += e;
                    if ((labr[i16] == labc[n]) && !diag) pos_p[i16] += a;
                }
            }
    } else {
        #pragma unroll
        for (int m = 0; m < 4; ++m)
            #pragma unroll
            for (int n = 0; n < 4; ++n) {
                #pragma unroll
                for (int r = 0; r < 4; ++r) {
                    const float a   = acc[m][n][r];
                    const int   i16 = m * 4 + r;
                    const float e   = __builtin_amdgcn_exp2f(a * C1);
                    const float pa  = (labr[i16] == labc[n]) ? a : 0.f;
                    sum_p[i16] += e;
                    pos_p[i16] += pa;
                    csum[n]    += e;
                    cpos[n]    += pa;
                }
            }
    }

    // row-side: 4-step transpose-reduce butterfly (2 arrays); lane j owns row j.
    #pragma unroll
    for (int bb = 1; bb <= 8; bb <<= 1) {
        const bool hi = (j & bb) != 0;
        #pragma unroll
        for (int k = 0; k < 8; ++k) {
            if (k < 16 / (2 * bb)) {
                const float eK = hi ? sum_p[2*k+1] : sum_p[2*k];
                const float eS = hi ? sum_p[2*k]   : sum_p[2*k+1];
                sum_p[k] = eK + __shfl_xor(eS, bb, 16);
                const float pK = hi ? pos_p[2*k+1] : pos_p[2*k];
                const float pS = hi ? pos_p[2*k]   : pos_p[2*k+1];
                pos_p[k] = pK + __shfl_xor(pS, bb, 16);
            }
        }
    }
    {
        // lane (t*16+j) owns row i16 = j: row = rowq + (j>>2)*16 + (j&3)
        const int rowS = rowq + ((j >> 2) << 4) + (j & 3);
        pp[(size_t)(ct * 2 + wc) * N_ROWS + rowS] = make_float2(sum_p[0], pos_p[0]);
    }

    // col-side (off-diag only): reduce across 4 lane-groups -> pp[rt*2+wr][col]
    if (!isDiag) {
        #pragma unroll
        for (int n = 0; n < 4; ++n) {
            float se = csum[n], pq = cpos[n];
            se += __shfl_xor(se, 16, 64); se += __shfl_xor(se, 32, 64);
            pq += __shfl_xor(pq, 16, 64); pq += __shfl_xor(pq, 32, 64);
            if (lane < 16) {
                const int gcol = col0 + n * 16;
                pp[(size_t)(rt * 2 + wr) * N_ROWS + gcol] = make_float2(se, pq);
            }
        }
    }
}

// ---------------- kernel 3: fused finalize ----------------
// cnt from per-block label histogram (cnt[row] = hist[lab[row]]-1).
__global__ __launch_bounds__(1024) void finalize_kernel(
    const float2* __restrict__ pp, const int* __restrict__ labels,
    float* __restrict__ out)
{
    __shared__ int   hist[NCLS];
    __shared__ float sh0[1024], sh1[1024];
    __shared__ float w4[4];

    const int tid = threadIdx.x;

    for (int i = tid; i < NCLS; i += 1024) hist[i] = 0;
    __syncthreads();
    for (int i = tid; i < N_ROWS; i += 1024) atomicAdd(&hist[labels[i]], 1);

    const int r   = tid & 255;
    const int q   = tid >> 8;
    const int row = blockIdx.x * 256 + r;

    float s = 0.f, p = 0.f;
    #pragma unroll 8
    for (int sl = q * 32; sl < q * 32 + 32; ++sl) {
        const float2 v = pp[(size_t)sl * N_ROWS + row];
        s += v.x;
        p += v.y;
    }
    sh0[tid] = s; sh1[tid] = p;
    __syncthreads();

    float per = 0.f;
    if (tid < 256) {
        s = sh0[tid] + sh0[tid + 256] + sh0[tid + 512] + sh0[tid + 768];
        p = sh1[tid] + sh1[tid + 256] + sh1[tid + 512] + sh1[tid + 768];
        const int c = hist[labels[row]] - 1;
        per = (c > 0) ? (logf(s) - (SCL * p) / (float)c) : 0.f;
    }
    #pragma unroll
    for (int off = 32; off > 0; off >>= 1) per += __shfl_down(per, off, 64);
    if (tid < 256 && (tid & 63) == 0) w4[tid >> 6] = per;
    __syncthreads();
    if (tid == 0)
        atomicAdd(out, w4[0] + w4[1] + w4[2] + w4[3]);
}

extern "C" void kernel_launch(void* const* d_in, const int* in_sizes, int n_in,
                              void* d_out, int out_size, void* d_ws, size_t ws_size,
                              hipStream_t stream) {
    const float* V      = (const float*)d_in[0];
    const int*   labels = (const int*)d_in[1];
    float*       out    = (float*)d_out;

    // ws layout: A4 4 MB | pp (float2) 8 MB
    unsigned char* A4 = (unsigned char*)d_ws;
    float2* pp = (float2*)((char*)d_ws + (size_t)N_ROWS * RPB);

    norm_kernel<<<N_ROWS / 4, 256, 0, stream>>>(V, A4, out);
    sim_kernel<<<NPAIR, 256, 0, stream>>>(A4, labels, pp);
    finalize_kernel<<<N_ROWS / 256, 1024, 0, stream>>>(pp, labels, out);
}

// Round 22
// 51.844 us; speedup vs baseline: 1.4923x; 1.4923x over previous
//
#include <hip/hip_runtime.h>
#include <hip/hip_bf16.h>
#include <stdint.h>

#define N_ROWS 8192
#define DIM    1024
#define INV_T  14.2857142857142857f   // 1/0.07
#define SCL    (INV_T / 1024.0f)      // acc holds 1024*sim (values packed as 32*x)
#define C1     (SCL * 1.44269504088896f)  // SCL * log2(e): e = exp2(acc*C1)
#define NCLS   1000

#define BM   128
#define RPB  512                 // row pitch bytes (fp4: DIM/2)
#define TKB  64                  // K-tile bytes per row (128 k-elems * 0.5B)
#define NTILE  (N_ROWS / BM)     // 64
#define NSLICE (2 * NTILE)       // 128 col-slices of 64
#define NKT    8                 // 1024 / 128
#define NPAIR  2080              // 64 diag + 64*63/2 off-diag
#define PER_XCD (NPAIR / 8)      // 260

typedef int   i32x4 __attribute__((ext_vector_type(4)));
typedef int   i32x8 __attribute__((ext_vector_type(8)));
typedef float f32x4 __attribute__((ext_vector_type(4)));

// e2m1 encode of y (round-to-nearest): values 0,.5,1,1.5,2,3,4,6 + sign bit
__device__ __forceinline__ unsigned e2m1(float y) {
    const float a = fabsf(y);
    unsigned c = a < 0.25f ? 0u : a < 0.75f ? 1u : a < 1.25f ? 2u :
                 a < 1.75f ? 3u : a < 2.5f  ? 4u : a < 3.5f  ? 5u :
                 a < 5.0f  ? 6u : 7u;
    return c | (y < 0.f ? 8u : 0u);
}

// ---------------- kernel 1: row-normalize f32 -> fp4 e2m1 (x32 prescale) ----
// One WAVE per row. Block 0 / thread 0 also zeroes out[0].
__global__ __launch_bounds__(256) void norm_kernel(
    const float* __restrict__ V, unsigned char* __restrict__ A4,
    float* __restrict__ out)
{
    if (blockIdx.x == 0 && threadIdx.x == 0) out[0] = 0.f;

    const int wid  = threadIdx.x >> 6;
    const int lane = threadIdx.x & 63;
    const int row  = blockIdx.x * 4 + wid;

    const float4* vp = (const float4*)(V + (size_t)row * DIM);
    float4 v[4];
    float ss = 0.f;
    #pragma unroll
    for (int i = 0; i < 4; ++i) {
        v[i] = vp[lane + i * 64];
        ss += v[i].x*v[i].x + v[i].y*v[i].y + v[i].z*v[i].z + v[i].w*v[i].w;
    }
    #pragma unroll
    for (int off = 1; off < 64; off <<= 1) ss += __shfl_xor(ss, off, 64);
    const float inv = 32.0f / sqrtf(ss);

    unsigned short op[4];
    #pragma unroll
    for (int i = 0; i < 4; ++i) {
        const unsigned e0 = e2m1(v[i].x * inv), e1 = e2m1(v[i].y * inv);
        const unsigned e2 = e2m1(v[i].z * inv), e3 = e2m1(v[i].w * inv);
        op[i] = (unsigned short)(e0 | (e1 << 4) | (e2 << 8) | (e3 << 12));
    }
    unsigned char* dst = A4 + (size_t)row * RPB;
    #pragma unroll
    for (int i = 0; i < 4; ++i)
        ((unsigned short*)dst)[lane + i * 64] = op[i];
}

// ---------------- kernel 2: fused symmetric sim GEMM (MX-fp4) + epilogue ----------------
// R20 configuration (best of session, 52.1us total). __launch_bounds__(256,3)
// is the toolchain's sweet spot: (256,4) -> 64-VGPR cap, spills; bare ->
// compiler inflates to 148 VGPR, occupancy 9% (R21). (256,3) -> 84 VGPR,
// 3 blocks/CU. Shell: dbuf 2x8KB LDS via global_load_lds, ONE barrier/K-tile,
// supertile-banded XCD-contiguous pair map, fp4-MX MFMA (scale=1.0),
// butterfly transpose-reduce epilogue, float2-packed transposed partials.
__global__ __launch_bounds__(256, 3) void sim_kernel(
    const unsigned char* __restrict__ A4, const int* __restrict__ labels,
    float2* __restrict__ pp)
{
    __shared__ __align__(16) unsigned char As[2][BM * TKB];   // 2 x 8 KB
    __shared__ __align__(16) unsigned char Bs[2][BM * TKB];   // 2 x 8 KB

    // ---- supertile pair decode (uniform per block, scalar) ----
    const int b = blockIdx.x;                    // 0..2079
    const int v = (b & 7) * PER_XCD + (b >> 3);  // XCD-contiguous virtual index
    int rem = v, RT = 0, rowsz = 36 + 7 * 64;    // ST-row RT size
    while (rem >= rowsz) { rem -= rowsz; ++RT; rowsz -= 64; }
    int rt, ct;
    if (rem < 36) {                              // diagonal supertile
        int i = 0, left = 8;
        while (rem >= left) { rem -= left; ++i; --left; }
        rt = RT * 8 + i;  ct = RT * 8 + i + rem;
    } else {                                     // off-diagonal supertile
        const int o  = rem - 36;
        const int CT = RT + 1 + (o >> 6);
        const int w  = o & 63;
        rt = RT * 8 + (w >> 3);
        ct = CT * 8 + (w & 7);
    }
    const bool isDiag = (rt == ct);

    const int tid  = threadIdx.x;
    const int lane = tid & 63;
    const int wid  = tid >> 6;
    const int wr   = wid >> 1;      // wave row 0..1
    const int wc   = wid & 1;       // wave col 0..1

    const int rbase = rt * BM;
    const int cbase = ct * BM;

    const int t = lane >> 4;        // K-group 0..3 / row sub-block
    const int j = lane & 15;

    const int rowq = rbase + wr * 64 + (t << 2);
    const int col0 = cbase + wc * 64 + j;

    int labr[16];
    #pragma unroll
    for (int m = 0; m < 4; ++m)
        #pragma unroll
        for (int r = 0; r < 4; ++r)
            labr[m * 4 + r] = labels[rowq + m * 16 + r];
    int labc[4];
    #pragma unroll
    for (int n = 0; n < 4; ++n) labc[n] = labels[col0 + n * 16];

    f32x4 acc[4][4];
    #pragma unroll
    for (int m = 0; m < 4; ++m)
        #pragma unroll
        for (int n = 0; n < 4; ++n)
            acc[m][n] = (f32x4){0.f, 0.f, 0.f, 0.f};

    // staging: linear LDS dest; source 16B-chunk XOR-swizzled with
    // f(row) = (row&3)^((row>>2)&3); read applies the same XOR.
    const unsigned char* sgA[2];
    const unsigned char* sgB[2];
    #pragma unroll
    for (int i = 0; i < 2; ++i) {
        const int c    = i * 256 + tid;
        const int rowc = c >> 2;
        const int kcs  = (c & 3) ^ (rowc & 3) ^ ((rowc >> 2) & 3);
        sgA[i] = A4 + (size_t)(rbase + rowc) * RPB + kcs * 16;
        sgB[i] = A4 + (size_t)(cbase + rowc) * RPB + kcs * 16;
    }
    #define STAGE(buf, kOff)                                                       \
    {                                                                              \
        _Pragma("unroll")                                                          \
        for (int i = 0; i < 2; ++i) {                                              \
            const int ldsOff = i * 4096 + wid * 1024;   /* +lane*16 by HW */       \
            __builtin_amdgcn_global_load_lds(                                      \
                (const __attribute__((address_space(1))) void*)(sgA[i] + (kOff)),  \
                (__attribute__((address_space(3))) void*)(As[buf] + ldsOff),       \
                16, 0, 0);                                                         \
            __builtin_amdgcn_global_load_lds(                                      \
                (const __attribute__((address_space(1))) void*)(sgB[i] + (kOff)),  \
                (__attribute__((address_space(3))) void*)(Bs[buf] + ldsOff),       \
                16, 0, 0);                                                         \
        }                                                                          \
    }

    // read-side chunk offset: f(row) = (j&3)^((j>>2)&3), indep. of m/n.
    const int ph = ((t ^ (j & 3) ^ ((j >> 2) & 3)) << 4);

    const i32x4 Z4 = (i32x4){0, 0, 0, 0};

    STAGE(0, 0);
    __syncthreads();                // tile 0 resident

    int cur = 0;
    for (int kt = 0; kt < NKT; ++kt) {
        // ---- pull all fragments of tile kt from buf[cur]
        i32x8 a8[4], b8[4];
        #pragma unroll
        for (int m = 0; m < 4; ++m) {
            const int rowa = wr * 64 + m * 16 + j;
            i32x4 q = *(const i32x4*)(As[cur] + rowa * TKB + ph);
            a8[m] = __builtin_shufflevector(q, Z4, 0, 1, 2, 3, 4, 5, 6, 7);
        }
        #pragma unroll
        for (int n = 0; n < 4; ++n) {
            const int rowb = wc * 64 + n * 16 + j;
            i32x4 q = *(const i32x4*)(Bs[cur] + rowb * TKB + ph);
            b8[n] = __builtin_shufflevector(q, Z4, 0, 1, 2, 3, 4, 5, 6, 7);
        }

        // ---- prefetch next tile into the other buffer (no hazard with reads)
        if (kt + 1 < NKT) STAGE(cur ^ 1, (kt + 1) * TKB);

        __builtin_amdgcn_s_setprio(1);
        #pragma unroll
        for (int m = 0; m < 4; ++m)
            #pragma unroll
            for (int n = 0; n < 4; ++n)
                acc[m][n] = __builtin_amdgcn_mfma_scale_f32_16x16x128_f8f6f4(
                    a8[m], b8[n], acc[m][n],
                    4 /*A fmt fp4*/, 4 /*B fmt fp4*/,
                    0, 0x7F /*scaleA = 2^0*/, 0, 0x7F /*scaleB = 2^0*/);
        __builtin_amdgcn_s_setprio(0);

        // single barrier per K-tile: drains lgkm (reads of cur done block-wide)
        // and vmcnt (prefetch into cur^1 landed block-wide).
        __syncthreads();
        cur ^= 1;
    }

    // ---------------- epilogue (sum of exp + raw-acc positive sum) ----------
    float sum_p[16], pos_p[16];
    #pragma unroll
    for (int i = 0; i < 16; ++i) { sum_p[i] = 0.f; pos_p[i] = 0.f; }
    float csum[4], cpos[4];
    #pragma unroll
    for (int n = 0; n < 4; ++n) { csum[n] = 0.f; cpos[n] = 0.f; }

    if (isDiag) {
        #pragma unroll
        for (int m = 0; m < 4; ++m)
            #pragma unroll
            for (int n = 0; n < 4; ++n) {
                const int gcol = col0 + n * 16;
                #pragma unroll
                for (int r = 0; r < 4; ++r) {
                    const float a    = acc[m][n][r];
                    const int   i16  = m * 4 + r;
                    const int   grow = rowq + m * 16 + r;
                    const bool  diag = (grow == gcol);
                    const float e    = diag ? 0.f : __builtin_amdgcn_exp2f(a * C1);
                    sum_p[i16] += e;
                    if ((labr[i16] == labc[n]) && !diag) pos_p[i16] += a;
                }
            }
    } else {
        #pragma unroll
        for (int m = 0; m < 4; ++m)
            #pragma unroll
            for (int n = 0; n < 4; ++n) {
                #pragma unroll
                for (int r = 0; r < 4; ++r) {
                    const float a   = acc[m][n][r];
                    const int   i16 = m * 4 + r;
                    const float e   = __builtin_amdgcn_exp2f(a * C1);
                    const float pa  = (labr[i16] == labc[n]) ? a : 0.f;
                    sum_p[i16] += e;
                    pos_p[i16] += pa;
                    csum[n]    += e;
                    cpos[n]    += pa;
                }
            }
    }

    // row-side: 4-step transpose-reduce butterfly (2 arrays); lane j owns row j.
    #pragma unroll
    for (int bb = 1; bb <= 8; bb <<= 1) {
        const bool hi = (j & bb) != 0;
        #pragma unroll
        for (int k = 0; k < 8; ++k) {
            if (k < 16 / (2 * bb)) {
                const float eK = hi ? sum_p[2*k+1] : sum_p[2*k];
                const float eS = hi ? sum_p[2*k]   : sum_p[2*k+1];
                sum_p[k] = eK + __shfl_xor(eS, bb, 16);
                const float pK = hi ? pos_p[2*k+1] : pos_p[2*k];
                const float pS = hi ? pos_p[2*k]   : pos_p[2*k+1];
                pos_p[k] = pK + __shfl_xor(pS, bb, 16);
            }
        }
    }
    {
        // lane (t*16+j) owns row i16 = j: row = rowq + (j>>2)*16 + (j&3)
        const int rowS = rowq + ((j >> 2) << 4) + (j & 3);
        pp[(size_t)(ct * 2 + wc) * N_ROWS + rowS] = make_float2(sum_p[0], pos_p[0]);
    }

    // col-side (off-diag only): reduce across 4 lane-groups -> pp[rt*2+wr][col]
    if (!isDiag) {
        #pragma unroll
        for (int n = 0; n < 4; ++n) {
            float se = csum[n], pq = cpos[n];
            se += __shfl_xor(se, 16, 64); se += __shfl_xor(se, 32, 64);
            pq += __shfl_xor(pq, 16, 64); pq += __shfl_xor(pq, 32, 64);
            if (lane < 16) {
                const int gcol = col0 + n * 16;
                pp[(size_t)(rt * 2 + wr) * N_ROWS + gcol] = make_float2(se, pq);
            }
        }
    }
}

// ---------------- kernel 3: fused finalize ----------------
// cnt from per-block label histogram (cnt[row] = hist[lab[row]]-1).
__global__ __launch_bounds__(1024) void finalize_kernel(
    const float2* __restrict__ pp, const int* __restrict__ labels,
    float* __restrict__ out)
{
    __shared__ int   hist[NCLS];
    __shared__ float sh0[1024], sh1[1024];
    __shared__ float w4[4];

    const int tid = threadIdx.x;

    for (int i = tid; i < NCLS; i += 1024) hist[i] = 0;
    __syncthreads();
    for (int i = tid; i < N_ROWS; i += 1024) atomicAdd(&hist[labels[i]], 1);

    const int r   = tid & 255;
    const int q   = tid >> 8;
    const int row = blockIdx.x * 256 + r;

    float s = 0.f, p = 0.f;
    #pragma unroll 8
    for (int sl = q * 32; sl < q * 32 + 32; ++sl) {
        const float2 v = pp[(size_t)sl * N_ROWS + row];
        s += v.x;
        p += v.y;
    }
    sh0[tid] = s; sh1[tid] = p;
    __syncthreads();

    float per = 0.f;
    if (tid < 256) {
        s = sh0[tid] + sh0[tid + 256] + sh0[tid + 512] + sh0[tid + 768];
        p = sh1[tid] + sh1[tid + 256] + sh1[tid + 512] + sh1[tid + 768];
        const int c = hist[labels[row]] - 1;
        per = (c > 0) ? (logf(s) - (SCL * p) / (float)c) : 0.f;
    }
    #pragma unroll
    for (int off = 32; off > 0; off >>= 1) per += __shfl_down(per, off, 64);
    if (tid < 256 && (tid & 63) == 0) w4[tid >> 6] = per;
    __syncthreads();
    if (tid == 0)
        atomicAdd(out, w4[0] + w4[1] + w4[2] + w4[3]);
}

extern "C" void kernel_launch(void* const* d_in, const int* in_sizes, int n_in,
                              void* d_out, int out_size, void* d_ws, size_t ws_size,
                              hipStream_t stream) {
    const float* V      = (const float*)d_in[0];
    const int*   labels = (const int*)d_in[1];
    float*       out    = (float*)d_out;

    // ws layout: A4 4 MB | pp (float2) 8 MB
    unsigned char* A4 = (unsigned char*)d_ws;
    float2* pp = (float2*)((char*)d_ws + (size_t)N_ROWS * RPB);

    norm_kernel<<<N_ROWS / 4, 256, 0, stream>>>(V, A4, out);
    sim_kernel<<<NPAIR, 256, 0, stream>>>(A4, labels, pp);
    finalize_kernel<<<N_ROWS / 256, 1024, 0, stream>>>(pp, labels, out);
}